// Round 10
// baseline (502.192 us; speedup 1.0000x reference)
//
#include <hip/hip_runtime.h>

#define NB 16      // B
#define NN 1024    // N
#define ND 16      // D
#define NCI 128    // CI
#define NCO 128    // CO
#define BN_ROWS (NB*NN)
#define MAXDEG 128
#define VOFF_ADJ (NB*ND*NCO)   // adj_out offset in d_out (floats)

__device__ __forceinline__ void fma4(float4& a, float s, const float4& w) {
    a.x = fmaf(s, w.x, a.x); a.y = fmaf(s, w.y, a.y);
    a.z = fmaf(s, w.z, a.z); a.w = fmaf(s, w.w, a.w);
}
__device__ __forceinline__ void add4(float4& a, const float4& b) {
    a.x += b.x; a.y += b.y; a.z += b.z; a.w += b.w;
}

// ---------------- pre1: BN partial stats (blocks 0..255) + W transpose (256..271) ----------------
__global__ __launch_bounds__(256) void k_pre1(const float* __restrict__ x,
                                              float* __restrict__ pbn,
                                              const float* __restrict__ W,
                                              float* __restrict__ Wt) {
    __shared__ float4 ls[8][32], lq[8][32];
    __shared__ float tile[32][33];
    int t = threadIdx.x;
    if (blockIdx.x < 256) {
        int q = t & 31, rg = t >> 5;
        int row0 = blockIdx.x * 64;
        const float4* x4 = (const float4*)x;
        float4 s = make_float4(0, 0, 0, 0), sq = make_float4(0, 0, 0, 0);
        for (int r = rg; r < 64; r += 8) {
            float4 v = x4[(size_t)(row0 + r) * 32 + q];
            s.x += v.x; s.y += v.y; s.z += v.z; s.w += v.w;
            sq.x = fmaf(v.x, v.x, sq.x); sq.y = fmaf(v.y, v.y, sq.y);
            sq.z = fmaf(v.z, v.z, sq.z); sq.w = fmaf(v.w, v.w, sq.w);
        }
        ls[rg][q] = s; lq[rg][q] = sq;
        __syncthreads();
        if (t < 32) {
            float4 a = ls[0][t];
            #pragma unroll
            for (int r = 1; r < 8; ++r) add4(a, ls[r][t]);
            ((float4*)(pbn + (size_t)blockIdx.x * 256))[t] = a;
        } else if (t < 64) {
            int qq = t - 32;
            float4 a = lq[0][qq];
            #pragma unroll
            for (int r = 1; r < 8; ++r) add4(a, lq[r][qq]);
            ((float4*)(pbn + (size_t)blockIdx.x * 256 + 128))[qq] = a;
        }
    } else {
        int d = blockIdx.x - 256;
        int r = t >> 5, cq = t & 31;
        const float* Wd = W + (size_t)d * NCI * NCO;
        float* Wtd = Wt + (size_t)d * NCI * NCO;
        for (int ti = 0; ti < 4; ++ti)
            for (int tj = 0; tj < 4; ++tj) {
                __syncthreads();
                for (int rr = r; rr < 32; rr += 8)
                    tile[rr][cq] = Wd[(size_t)(ti * 32 + rr) * 128 + tj * 32 + cq];
                __syncthreads();
                for (int rr = r; rr < 32; rr += 8)
                    Wtd[(size_t)(tj * 32 + rr) * 128 + ti * 32 + cq] = tile[cq][rr];
            }
    }
}

// ---------------- pre2: neighbor lists (0..16383) + BN finalize (16384..16399) ----------------
__global__ __launch_bounds__(256) void k_pre2(const float* __restrict__ adj,
        float* __restrict__ dis, int* __restrict__ nbr_idx, int* __restrict__ nbr_cnt,
        float* __restrict__ selfd, const float* __restrict__ pbn,
        const float* __restrict__ gamma, const float* __restrict__ beta,
        float* __restrict__ ss, float* __restrict__ xm) {
    int t = threadIdx.x;
    if (blockIdx.x < NB * NN) {
        int bm = blockIdx.x;              // b*N + m
        int m = bm & (NN - 1);
        const float4* row4 = (const float4*)(adj + (size_t)bm * NN);
        __shared__ int cnt;
        __shared__ int idx[MAXDEG];
        if (t == 0) { cnt = 1; idx[0] = m; }   // forced self-loop
        __syncthreads();
        float4 v = row4[t];
        int n0 = t * 4;
        float av[4] = {v.x, v.y, v.z, v.w};
        #pragma unroll
        for (int j = 0; j < 4; ++j) {
            int n = n0 + j;
            if (n == m) {
                selfd[bm] = (av[j] > 0.5f) ? 1.f : 0.f;
            } else if (av[j] > 0.5f) {
                int p = atomicAdd(&cnt, 1);
                if (p < MAXDEG) idx[p] = n;
            }
        }
        __syncthreads();
        int c = min(cnt, MAXDEG);
        if (t == 0) {
            nbr_cnt[bm] = c;
            dis[bm] = rsqrtf((float)c);
        }
        for (int k = t; k < c; k += 256) nbr_idx[(size_t)bm * MAXDEG + k] = idx[k];
    } else {
        int b = blockIdx.x - NB * NN;   // 0..15
        if (t < 128) {
            float s = 0.f, sq = 0.f, sb = 0.f;
            for (int blk = 0; blk < 256; ++blk) {
                float v = pbn[(size_t)blk * 256 + t];
                s += v;
                sq += pbn[(size_t)blk * 256 + 128 + t];
                sb += ((blk >> 4) == b) ? v : 0.f;
            }
            float mu = s * (1.f / BN_ROWS);
            float var = sq * (1.f / BN_ROWS) - mu * mu;
            float sc = gamma[t] * rsqrtf(var + 1e-5f);
            float sh = beta[t] - mu * sc;
            if (b == 0) { ss[t] = sc; ss[128 + t] = sh; }
            xm[b * NCI + t] = sb * (1.f / NN) * sc + sh;
        }
    }
}

// ---------------- y = a_norm @ (x*sc+sh): one row per block, XCD-swizzled ----------------
__global__ void k_y(const float* __restrict__ x, const float* __restrict__ ss,
                    const float* __restrict__ dis, const int* __restrict__ nbr_idx,
                    const int* __restrict__ nbr_cnt, float* __restrict__ y) {
    int l = blockIdx.x;
    int idx0 = l >> 3;
    int b = (l & 7) + ((idx0 >> 10) << 3);
    int m = idx0 & 1023;
    int bm = (b << 10) + m;
    int t = threadIdx.x;  // 128
    int q = t & 31, ng = t >> 5;
    __shared__ float sw[MAXDEG];
    __shared__ int sIdx[MAXDEG];
    int cnt = nbr_cnt[bm];
    float dm = dis[bm];
    for (int k = t; k < cnt; k += 128) {
        int n = nbr_idx[(size_t)bm * MAXDEG + k];
        sIdx[k] = n;
        sw[k] = dm * dis[(b << 10) + n];
    }
    __syncthreads();
    const float4* xb = (const float4*)(x + ((size_t)(b << 10)) * NCI);
    float4 acc = make_float4(0, 0, 0, 0);
    float wsum = 0.f;
    for (int k = ng; k < cnt; k += 4) {
        float w = sw[k];
        float4 v = xb[(size_t)sIdx[k] * 32 + q];
        fma4(acc, w, v);
        wsum += w;
    }
    __shared__ float4 lacc[4][32];
    __shared__ float lws[4];
    lacc[ng][q] = acc;
    if (q == 0) lws[ng] = wsum;
    __syncthreads();
    if (t < 32) {
        float4 a = lacc[0][t];
        add4(a, lacc[1][t]); add4(a, lacc[2][t]); add4(a, lacc[3][t]);
        float wst = lws[0] + lws[1] + lws[2] + lws[3];
        float4 sc = ((const float4*)ss)[t];
        float4 sh = ((const float4*)(ss + 128))[t];
        float4 o;
        o.x = sc.x * a.x + sh.x * wst;
        o.y = sc.y * a.y + sh.y * wst;
        o.z = sc.z * a.z + sh.z * wst;
        o.w = sc.w * a.w + sh.w * wst;
        ((float4*)(y + (size_t)bm * NCI))[t] = o;
    }
}

// ---------------- k_route: ENTIRE routing per batch b in ONE block (1024 thr, 16 waves) --------
// All phase syncs are __syncthreads(); no cross-block dependency anywhere.
__global__ __launch_bounds__(1024) void k_route(const float* __restrict__ y,
        const float* __restrict__ W, const float* __restrict__ Wt,
        const float* __restrict__ bias, const float* __restrict__ xm,
        float* __restrict__ blog, float* __restrict__ cglob,
        float* __restrict__ outv) {
    int b = blockIdx.x;
    int t = threadIdx.x;
    int wv = t >> 6;      // wave id 0..15  (== d in SV phases)
    int ln = t & 63;

    __shared__ float sy[32 * 132];     // y chunk (row pad 4) / G0 scratch  16896B
    __shared__ float hb[16][132];      // h                                  8448B
    __shared__ float gb[16][129];      // g accumulator                      8256B
    __shared__ float svv[16][132];     // v                                  8448B
    __shared__ float scd[32][17];      // per-chunk b-logits then c          2176B
    __shared__ float csum[16], hbbs[16];

    const float4* yb4 = (const float4*)(y + (((size_t)b) << 10) * NCI);

    // ---- G0: gb[0][:] = colsum(y[b]) / 16 ; csum[:] = 64
    {
        int q = t & 31, rg = t >> 5;   // 32 row-groups x 32 f4-cols
        float4 s = make_float4(0, 0, 0, 0);
        for (int r = rg; r < 1024; r += 32) add4(s, yb4[(size_t)r * 32 + q]);
        ((float4*)sy)[rg * 32 + q] = s;
        if (t < 16) csum[t] = 64.f;
        __syncthreads();
        if (t < 32) {
            float4 a = ((float4*)sy)[t];
            for (int r = 1; r < 32; ++r) add4(a, ((float4*)sy)[r * 32 + t]);
            a.x *= (1.f / 16.f); a.y *= (1.f / 16.f);
            a.z *= (1.f / 16.f); a.w *= (1.f / 16.f);
            ((float4*)&gb[0][0])[t] = a;
        }
        __syncthreads();
    }

    for (int iter = 0; iter < 3; ++iter) {
        int guni = (iter == 0);
        int final_it = (iter == 2);
        int d = wv;
        // ---- SV-A: s[d][o] = sum_i g[i] W[d,i,o] + csum[d]*bias[d,o]   (wave d, lane = o-pair)
        {
            const float* grow = gb[guni ? 0 : d];
            const float2* W2 = (const float2*)(W + (size_t)d * NCI * NCO);
            const float2* B2 = (const float2*)(bias + d * NCO);
            float2 acc = make_float2(0.f, 0.f);
            #pragma unroll 4
            for (int i = 0; i < 128; ++i) {
                float gv = grow[i];
                float2 w2 = W2[i * 64 + ln];
                acc.x = fmaf(gv, w2.x, acc.x);
                acc.y = fmaf(gv, w2.y, acc.y);
            }
            float cs = csum[d];
            float2 b2 = B2[ln];
            acc.x = fmaf(cs, b2.x, acc.x);
            acc.y = fmaf(cs, b2.y, acc.y);
            if (final_it) {
                int o0 = ln * 2;
                float s0 = acc.x + xm[b * NCO + o0];
                float s1 = acc.y + xm[b * NCO + o0 + 1];
                float q0 = s0 * s0, q1 = s1 * s1;
                outv[(size_t)(b * 16 + d) * NCO + o0]     = (q0 / (1.f + q0)) * s0 * rsqrtf(q0 + 1e-8f);
                outv[(size_t)(b * 16 + d) * NCO + o0 + 1] = (q1 / (1.f + q1)) * s1 * rsqrtf(q1 + 1e-8f);
            } else {
                float val = acc.x * acc.x + acc.y * acc.y;
                #pragma unroll
                for (int m2 = 32; m2 >= 1; m2 >>= 1) val += __shfl_xor(val, m2);
                float fac = (val / (1.f + val)) * rsqrtf(val + 1e-8f);
                float v0 = fac * acc.x, v1 = fac * acc.y;
                svv[d][ln * 2] = v0; svv[d][ln * 2 + 1] = v1;
                float pb = b2.x * v0 + b2.y * v1;
                #pragma unroll
                for (int m2 = 32; m2 >= 1; m2 >>= 1) pb += __shfl_xor(pb, m2);
                if (ln == 0) hbbs[d] = pb;
            }
        }
        if (final_it) break;
        __syncthreads();
        // ---- SV-C: h[d][i] = sum_o Wt[d,o,i] v[o]
        {
            const float2* Wt2 = (const float2*)(Wt + (size_t)d * NCI * NCO);
            float2 acc = make_float2(0.f, 0.f);
            #pragma unroll 4
            for (int o = 0; o < 128; ++o) {
                float vv = svv[d][o];
                float2 w2 = Wt2[o * 64 + ln];
                acc.x = fmaf(vv, w2.x, acc.x);
                acc.y = fmaf(vv, w2.y, acc.y);
            }
            hb[d][ln * 2] = acc.x; hb[d][ln * 2 + 1] = acc.y;
        }
        __syncthreads();
        // zero g/csum accumulators for next iteration
        {
            int j = t * 2;
            gb[j >> 7][j & 127] = 0.f;
            gb[(j + 1) >> 7][(j + 1) & 127] = 0.f;
            if (t < 16) csum[t] = 0.f;
        }
        __syncthreads();
        // ---- BUPD over 32 chunks of 32 rows
        for (int ch = 0; ch < 32; ++ch) {
            int n0 = ch * 32;
            {   // stage y chunk
                int row = t >> 5, col = t & 31;
                ((float4*)&sy[row * 132])[col] = yb4[(size_t)(n0 + row) * 32 + col];
            }
            __syncthreads();
            {   // dots: task=(nn,d), 2 threads per task
                int half = t & 1, task = t >> 1;
                int nn = task >> 4, dd = task & 15;
                const float* yr = &sy[nn * 132];
                const float* hr = &hb[dd][0];
                float acc = 0.f;
                int i0 = half * 64;
                #pragma unroll 4
                for (int i = i0; i < i0 + 64; i += 4) {
                    float4 a = *(const float4*)&yr[i];
                    float4 h4 = *(const float4*)&hr[i];
                    acc = fmaf(a.x, h4.x, acc);
                    acc = fmaf(a.y, h4.y, acc);
                    acc = fmaf(a.z, h4.z, acc);
                    acc = fmaf(a.w, h4.w, acc);
                }
                acc += __shfl_xor(acc, 1);
                if (half == 0) {
                    size_t gidx = (((size_t)b << 10) + n0 + nn) * ND + dd;
                    float bnew = acc + hbbs[dd] + (iter == 0 ? 0.f : blog[gidx]);
                    if (iter == 0) blog[gidx] = bnew;
                    scd[nn][dd] = bnew;
                }
            }
            __syncthreads();
            if (t < 32) {   // sparsemax per row
                float z[16], zs[16];
                #pragma unroll
                for (int d2 = 0; d2 < 16; ++d2) { z[d2] = scd[t][d2]; zs[d2] = z[d2]; }
                #pragma unroll
                for (int a = 0; a < 16; ++a) {
                    #pragma unroll
                    for (int b2 = a + 1; b2 < 16; ++b2) {
                        float hi = fmaxf(zs[a], zs[b2]);
                        float lo = fminf(zs[a], zs[b2]);
                        zs[a] = hi; zs[b2] = lo;
                    }
                }
                float cs = 0.f, tausum = 0.f;
                int kz = 1;
                #pragma unroll
                for (int k = 1; k <= 16; ++k) {
                    cs += zs[k - 1];
                    if (1.f + (float)k * zs[k - 1] > cs) { kz = k; tausum = cs; }
                }
                float tau = (tausum - 1.f) / (float)kz;
                #pragma unroll
                for (int d2 = 0; d2 < 16; ++d2) {
                    float cv = fmaxf(z[d2] - tau, 0.f);
                    scd[t][d2] = cv;
                    if (iter == 1)
                        cglob[(((size_t)b << 10) + n0 + t) * ND + d2] = cv;  // final c
                }
            }
            __syncthreads();
            {   // g/csum accumulation: g[d][i] += sum_nn c[nn,d]*y[nn,i]
                int i = t & 127, grp = t >> 7;
                int d0 = grp * 2;
                float a0 = 0.f, a1 = 0.f;
                for (int nn = 0; nn < 32; ++nn) {
                    float yv = sy[nn * 132 + i];
                    a0 = fmaf(scd[nn][d0], yv, a0);
                    a1 = fmaf(scd[nn][d0 + 1], yv, a1);
                }
                gb[d0][i] += a0;
                gb[d0 + 1][i] += a1;
            }
            if (t < 16) {
                float cs = 0.f;
                #pragma unroll 4
                for (int nn = 0; nn < 32; ++nn) cs += scd[nn][t];
                csum[t] += cs;
            }
            __syncthreads();
        }
    }
    // zero the adj_out region for k_adjc's atomics (deterministic each call)
    if (t < 256) outv[VOFF_ADJ + b * 256 + t] = 0.f;
}

// ---------------- adj_out: t2 gather + 16x16 partials, 512 blocks, atomics ----------------
__global__ __launch_bounds__(256) void k_adjc(const float* __restrict__ cglob,
        const int* __restrict__ nbr_idx, const int* __restrict__ nbr_cnt,
        const float* __restrict__ selfd, float* __restrict__ outv) {
    __shared__ float cm[32][17], tm[32][17];
    int t = threadIdx.x;
    int l = blockIdx.x, idx0 = l >> 3;
    int b = (l & 7) + ((idx0 >> 5) << 3);
    int j = idx0 & 31;
    for (int jj = t; jj < 32 * 16; jj += 256)
        cm[jj >> 4][jj & 15] = cglob[(((size_t)b << 10) + j * 32 + (jj >> 4)) * ND + (jj & 15)];
    __syncthreads();
    int w = t >> 6, tg = t & 63, nsub = tg >> 4, d = tg & 15;
    for (int mm = w; mm < 32; mm += 4) {
        int m = j * 32 + mm;
        int bm = (b << 10) + m;
        int cnt = nbr_cnt[bm];
        float acc = 0.f;
        for (int k = nsub; k < cnt; k += 4) {
            int n = nbr_idx[(size_t)bm * MAXDEG + k];
            acc += cglob[(((size_t)b << 10) + n) * ND + d];
        }
        acc += __shfl_xor(acc, 16);
        acc += __shfl_xor(acc, 32);
        if (tg < 16) {
            if (selfd[bm] == 0.f) acc -= cm[mm][d];
            tm[mm][d] = acc;
        }
    }
    __syncthreads();
    int d2 = t >> 4, e2 = t & 15;
    float s = 0.f;
    #pragma unroll 8
    for (int mm = 0; mm < 32; ++mm) s = fmaf(tm[mm][d2], cm[mm][e2], s);
    atomicAdd(&outv[VOFF_ADJ + b * 256 + t], s);
}

extern "C" void kernel_launch(void* const* d_in, const int* in_sizes, int n_in,
                              void* d_out, int out_size, void* d_ws, size_t ws_size,
                              hipStream_t stream) {
    const float* x     = (const float*)d_in[0];
    const float* adj   = (const float*)d_in[1];
    const float* gamma = (const float*)d_in[2];
    const float* beta  = (const float*)d_in[3];
    const float* W     = (const float*)d_in[4];
    const float* bias  = (const float*)d_in[5];
    float* out = (float*)d_out;

    char* wptr = (char*)d_ws;
    size_t used = 0;
    auto alloc = [&](size_t nbytes) -> void* {
        void* p = wptr + used;
        used += (nbytes + 255) & ~(size_t)255;
        return p;
    };
    float* pbn     = (float*)alloc((size_t)256 * 256 * 4);
    float* ss      = (float*)alloc(256 * 4);
    float* xm      = (float*)alloc((size_t)NB * NCI * 4);
    float* dis     = (float*)alloc((size_t)NB * NN * 4);
    float* selfd   = (float*)alloc((size_t)NB * NN * 4);
    int*   nbr_cnt = (int*)alloc((size_t)NB * NN * 4);
    float* Wt      = (float*)alloc((size_t)ND * NCI * NCO * 4);
    float* y       = (float*)alloc((size_t)NB * NN * NCI * 4);
    float* blog    = (float*)alloc((size_t)NB * NN * ND * 4);
    float* cglob   = (float*)alloc((size_t)NB * NN * ND * 4);
    int*   nbr_idx = (int*)alloc((size_t)NB * NN * MAXDEG * 4);
    if (used > ws_size) return;

    k_pre1<<<256 + ND, 256, 0, stream>>>(x, pbn, W, Wt);
    k_pre2<<<NB * NN + NB, 256, 0, stream>>>(adj, dis, nbr_idx, nbr_cnt, selfd,
                                             pbn, gamma, beta, ss, xm);
    k_y<<<NB * NN, 128, 0, stream>>>(x, ss, dis, nbr_idx, nbr_cnt, y);
    k_route<<<NB, 1024, 0, stream>>>(y, W, Wt, bias, xm, blog, cglob, out);
    k_adjc<<<NB * 32, 256, 0, stream>>>(cglob, nbr_idx, nbr_cnt, selfd, out);
}

// Round 11
// 128.135 us; speedup vs baseline: 3.9192x; 3.9192x over previous
//
#include <hip/hip_runtime.h>

#define NB 16      // B
#define NN 1024    // N
#define ND 16      // D
#define NCI 128    // CI
#define NCO 128    // CO
#define BN_ROWS (NB*NN)
#define MAXDEG 128
#define VOFF_ADJ (NB*ND*NCO)   // adj_out offset in d_out (floats)

__device__ __forceinline__ void fma4(float4& a, float s, const float4& w) {
    a.x = fmaf(s, w.x, a.x); a.y = fmaf(s, w.y, a.y);
    a.z = fmaf(s, w.z, a.z); a.w = fmaf(s, w.w, a.w);
}
__device__ __forceinline__ void add4(float4& a, const float4& b) {
    a.x += b.x; a.y += b.y; a.z += b.z; a.w += b.w;
}

// ---- pre1: BN partial stats (0..255) + W transpose (256..271) + nbr build (272..16655) --------
__global__ __launch_bounds__(256) void k_pre1(const float* __restrict__ x,
                                              float* __restrict__ pbn,
                                              const float* __restrict__ W,
                                              float* __restrict__ Wt,
                                              const float* __restrict__ adj,
                                              float* __restrict__ dis,
                                              int* __restrict__ nbr_idx,
                                              int* __restrict__ nbr_cnt,
                                              float* __restrict__ selfd) {
    __shared__ float4 ls[8][32], lq[8][32];
    __shared__ float tile[32][33];
    __shared__ int cnt;
    __shared__ int idx[MAXDEG];
    int t = threadIdx.x;
    if (blockIdx.x < 256) {
        int q = t & 31, rg = t >> 5;
        int row0 = blockIdx.x * 64;
        const float4* x4 = (const float4*)x;
        float4 s = make_float4(0, 0, 0, 0), sq = make_float4(0, 0, 0, 0);
        for (int r = rg; r < 64; r += 8) {
            float4 v = x4[(size_t)(row0 + r) * 32 + q];
            s.x += v.x; s.y += v.y; s.z += v.z; s.w += v.w;
            sq.x = fmaf(v.x, v.x, sq.x); sq.y = fmaf(v.y, v.y, sq.y);
            sq.z = fmaf(v.z, v.z, sq.z); sq.w = fmaf(v.w, v.w, sq.w);
        }
        ls[rg][q] = s; lq[rg][q] = sq;
        __syncthreads();
        if (t < 32) {
            float4 a = ls[0][t];
            #pragma unroll
            for (int r = 1; r < 8; ++r) add4(a, ls[r][t]);
            ((float4*)(pbn + (size_t)blockIdx.x * 256))[t] = a;
        } else if (t < 64) {
            int qq = t - 32;
            float4 a = lq[0][qq];
            #pragma unroll
            for (int r = 1; r < 8; ++r) add4(a, lq[r][qq]);
            ((float4*)(pbn + (size_t)blockIdx.x * 256 + 128))[qq] = a;
        }
    } else if (blockIdx.x < 272) {
        int d = blockIdx.x - 256;
        int r = t >> 5, cq = t & 31;
        const float* Wd = W + (size_t)d * NCI * NCO;
        float* Wtd = Wt + (size_t)d * NCI * NCO;
        for (int ti = 0; ti < 4; ++ti)
            for (int tj = 0; tj < 4; ++tj) {
                __syncthreads();
                for (int rr = r; rr < 32; rr += 8)
                    tile[rr][cq] = Wd[(size_t)(ti * 32 + rr) * 128 + tj * 32 + cq];
                __syncthreads();
                for (int rr = r; rr < 32; rr += 8)
                    Wtd[(size_t)(tj * 32 + rr) * 128 + ti * 32 + cq] = tile[cq][rr];
            }
    } else {
        int bm = blockIdx.x - 272;        // b*N + m
        int m = bm & (NN - 1);
        const float4* row4 = (const float4*)(adj + (size_t)bm * NN);
        if (t == 0) { cnt = 1; idx[0] = m; }   // forced self-loop
        __syncthreads();
        float4 v = row4[t];
        int n0 = t * 4;
        float av[4] = {v.x, v.y, v.z, v.w};
        #pragma unroll
        for (int j = 0; j < 4; ++j) {
            int n = n0 + j;
            if (n == m) {
                selfd[bm] = (av[j] > 0.5f) ? 1.f : 0.f;
            } else if (av[j] > 0.5f) {
                int p = atomicAdd(&cnt, 1);
                if (p < MAXDEG) idx[p] = n;
            }
        }
        __syncthreads();
        int c = min(cnt, MAXDEG);
        if (t == 0) {
            nbr_cnt[bm] = c;
            dis[bm] = rsqrtf((float)c);
        }
        for (int k = t; k < c; k += 256) nbr_idx[(size_t)bm * MAXDEG + k] = idx[k];
    }
}

// ---- pre2: BN finalize (blocks 0..15) + yraw gather (16..16399, XCD-swizzled) -----------------
// yraw[bm,:] = sum_n w_n x[n,:],  wsum[bm] = sum_n w_n   (affine sc/sh deferred to consumers)
__global__ void k_pre2(const float* __restrict__ x, const float* __restrict__ dis,
                       const int* __restrict__ nbr_idx, const int* __restrict__ nbr_cnt,
                       float* __restrict__ yraw, float* __restrict__ wsum,
                       const float* __restrict__ pbn, const float* __restrict__ gamma,
                       const float* __restrict__ beta, float* __restrict__ ss,
                       float* __restrict__ xm) {
    int t = threadIdx.x;  // 128
    if (blockIdx.x < 16) {
        int b = blockIdx.x;
        float s = 0.f, sq = 0.f, sb = 0.f;
        for (int blk = 0; blk < 256; ++blk) {
            float v = pbn[(size_t)blk * 256 + t];
            s += v;
            sq += pbn[(size_t)blk * 256 + 128 + t];
            sb += ((blk >> 4) == b) ? v : 0.f;
        }
        float mu = s * (1.f / BN_ROWS);
        float var = sq * (1.f / BN_ROWS) - mu * mu;
        float sc = gamma[t] * rsqrtf(var + 1e-5f);
        float sh = beta[t] - mu * sc;
        if (b == 0) { ss[t] = sc; ss[128 + t] = sh; }
        xm[b * NCI + t] = sb * (1.f / NN) * sc + sh;
        return;
    }
    int l = blockIdx.x - 16;
    int idx0 = l >> 3;
    int b = (l & 7) + ((idx0 >> 10) << 3);
    int m = idx0 & 1023;
    int bm = (b << 10) + m;
    int q = t & 31, ng = t >> 5;
    __shared__ float sw[MAXDEG];
    __shared__ int sIdx[MAXDEG];
    int cnt = nbr_cnt[bm];
    float dm = dis[bm];
    for (int k = t; k < cnt; k += 128) {
        int n = nbr_idx[(size_t)bm * MAXDEG + k];
        sIdx[k] = n;
        sw[k] = dm * dis[(b << 10) + n];
    }
    __syncthreads();
    const float4* xb = (const float4*)(x + ((size_t)(b << 10)) * NCI);
    float4 acc = make_float4(0, 0, 0, 0);
    float ws = 0.f;
    for (int k = ng; k < cnt; k += 4) {
        float w = sw[k];
        float4 v = xb[(size_t)sIdx[k] * 32 + q];
        fma4(acc, w, v);
        ws += w;
    }
    __shared__ float4 lacc[4][32];
    __shared__ float lws[4];
    lacc[ng][q] = acc;
    if (q == 0) lws[ng] = ws;
    __syncthreads();
    if (t < 32) {
        float4 a = lacc[0][t];
        add4(a, lacc[1][t]); add4(a, lacc[2][t]); add4(a, lacc[3][t]);
        ((float4*)(yraw + (size_t)bm * NCI))[t] = a;
        if (t == 0) wsum[bm] = lws[0] + lws[1] + lws[2] + lws[3];
    }
}

// ---- s->v->h fused. mode 0: g from yraw colsum (uniform c); 1: g from pg/pcs; 2: final v out --
// haccum: step-4 accumulates h into hbuf/hbb (for iteration 2's combined logits)
__device__ __forceinline__ void sv_phase(int b, int d, int t, int mode, int haccum,
    const float* __restrict__ gsrc, const float* __restrict__ wsum,
    const float* __restrict__ ss, const float* __restrict__ pcs,
    const float* __restrict__ W, const float* __restrict__ Wt,
    const float* __restrict__ bias, const float* __restrict__ xm,
    float* __restrict__ hbuf, float* __restrict__ hbb, float* __restrict__ outv,
    float* gl, float4 (*red)[32], float* redf, float* svec, float* vvv,
    float* csum_s, float* scal)
{
    // 1. g reduction
    if (mode == 0) {
        int q = t & 31, rg = t >> 5;
        const float4* yb = (const float4*)(gsrc + (((size_t)b) << 10) * NCI);
        float4 s = make_float4(0, 0, 0, 0);
        #pragma unroll 4
        for (int r = rg; r < 1024; r += 8) add4(s, yb[(size_t)r * 32 + q]);
        red[rg][q] = s;
        float w = 0.f;
        for (int r = t; r < 1024; r += 256) w += wsum[(b << 10) + r];
        redf[t] = w;
        if (t == 0) *csum_s = 64.f;
        __syncthreads();
        if (t < 32) {
            float4 a = red[0][t];
            #pragma unroll
            for (int r = 1; r < 8; ++r) add4(a, red[r][t]);
            float wst = 0.f;
            #pragma unroll 8
            for (int i = 0; i < 256; ++i) wst += redf[i];
            float4 sc = ((const float4*)ss)[t];
            float4 sh = ((const float4*)(ss + 128))[t];
            float4 g;
            g.x = (sc.x * a.x + sh.x * wst) * (1.f / 16.f);
            g.y = (sc.y * a.y + sh.y * wst) * (1.f / 16.f);
            g.z = (sc.z * a.z + sh.z * wst) * (1.f / 16.f);
            g.w = (sc.w * a.w + sh.w * wst) * (1.f / 16.f);
            ((float4*)gl)[t] = g;
        }
        __syncthreads();
    } else {
        int col = t & 127, half = t >> 7;
        float g = 0.f;
        #pragma unroll 4
        for (int ch = half * 16; ch < half * 16 + 16; ++ch)
            g += gsrc[(((size_t)b * 32 + ch) * 16 + d) * NCI + col];
        ((float*)red)[half * 128 + col] = g;
        if (t == 0) {
            float cs = 0.f;
            #pragma unroll
            for (int ch = 0; ch < 32; ++ch) cs += pcs[(b * 32 + ch) * 16 + d];
            *csum_s = cs;
        }
        __syncthreads();
        if (t < 128) gl[t] = ((float*)red)[t] + ((float*)red)[128 + t];
        __syncthreads();
    }

    // 2. s[o] = sum_i gl[i]*W[d,i,o] + csum*bias[o]
    {
        int q = t & 31, hh = t >> 5;
        const float4* Wd4 = (const float4*)(W + (size_t)d * NCI * NCO);
        float4 acc = make_float4(0, 0, 0, 0);
        for (int i = hh * 16; i < hh * 16 + 16; ++i)
            fma4(acc, gl[i], Wd4[(size_t)i * 32 + q]);
        red[hh][q] = acc;
    }
    __syncthreads();
    if (t < 32) {
        float4 a = red[0][t];
        #pragma unroll
        for (int r = 1; r < 8; ++r) add4(a, red[r][t]);
        float4 b4 = ((const float4*)(bias + d * NCO))[t];
        float cs = *csum_s;
        a.x = fmaf(cs, b4.x, a.x); a.y = fmaf(cs, b4.y, a.y);
        a.z = fmaf(cs, b4.z, a.z); a.w = fmaf(cs, b4.w, a.w);
        ((float4*)svec)[t] = a;
    }
    __syncthreads();

    if (mode == 2) {
        if (t < 128) {
            float sv2 = svec[t] + xm[b * NCO + t];
            float sq = sv2 * sv2;
            outv[(size_t)(b * 16 + d) * NCO + t] = (sq / (1.f + sq)) * sv2 * rsqrtf(sq + 1e-8f);
        }
        return;
    }

    // 3. squash over o
    redf[t] = (t < 128) ? svec[t] * svec[t] : 0.f;
    __syncthreads();
    if (t < 64) {
        float val = redf[t] + redf[t + 64] + redf[t + 128] + redf[t + 192];
        #pragma unroll
        for (int m2 = 32; m2 >= 1; m2 >>= 1) val += __shfl_xor(val, m2);
        if (t == 0) *scal = val;
    }
    __syncthreads();
    if (t < 128) {
        float tot = *scal;
        vvv[t] = (tot / (1.f + tot)) * svec[t] * rsqrtf(tot + 1e-8f);
    }
    __syncthreads();

    // 4. h[i] = sum_o Wt[d,o,i]*v[o]; hbb = dot(bias, v)  (accumulate if haccum)
    {
        int q = t & 31, hh = t >> 5;
        const float4* Wt4 = (const float4*)(Wt + (size_t)d * NCI * NCO);
        float4 acc = make_float4(0, 0, 0, 0);
        for (int o = hh * 16; o < hh * 16 + 16; ++o)
            fma4(acc, vvv[o], Wt4[(size_t)o * 32 + q]);
        red[hh][q] = acc;
    }
    redf[t] = (t < 128) ? bias[d * NCO + t] * vvv[t] : 0.f;
    __syncthreads();
    if (t < 32) {
        float4 a = red[0][t];
        #pragma unroll
        for (int r = 1; r < 8; ++r) add4(a, red[r][t]);
        float4* hp = (float4*)(hbuf + (size_t)(b * 16 + d) * NCI);
        if (haccum) add4(a, hp[t]);
        hp[t] = a;
    }
    if (t >= 64 && t < 128) {
        int tt = t - 64;
        float val = redf[tt] + redf[tt + 64] + redf[tt + 128] + redf[tt + 192];
        #pragma unroll
        for (int m2 = 32; m2 >= 1; m2 >>= 1) val += __shfl_xor(val, m2);
        if (tt == 0) hbb[b * 16 + d] = haccum ? (hbb[b * 16 + d] + val) : val;
    }
}

// grid 256, XCD-swizzled: b = (l&7) + 8*((l>>3)>>4), d = (l>>3)&15
__global__ __launch_bounds__(256) void k_sv(const float* __restrict__ gsrc,
        const float* __restrict__ wsum, const float* __restrict__ ss,
        const float* __restrict__ pcs, const float* __restrict__ W,
        const float* __restrict__ Wt, const float* __restrict__ bias,
        const float* __restrict__ xm, float* __restrict__ hbuf,
        float* __restrict__ hbb, float* __restrict__ outv, int mode, int haccum) {
    __shared__ float gl[128], svec[128], vvv[128];
    __shared__ float4 red[8][32];
    __shared__ float redf[256];
    __shared__ float csum_s, scal;
    int l = blockIdx.x, idx0 = l >> 3;
    int b = (l & 7) + ((idx0 >> 4) << 3);
    int d = idx0 & 15;
    sv_phase(b, d, threadIdx.x, mode, haccum, gsrc, wsum, ss, pcs, W, Wt, bias, xm,
             hbuf, hbb, outv, gl, red, redf, svec, vvv, &csum_s, &scal);
}

// ---- bgc: logits from running h-sum + sparsemax + g partials (block = (b,j32), swizzled) ------
__global__ __launch_bounds__(256) void k_bgc(const float* __restrict__ yraw,
        const float* __restrict__ wsum, const float* __restrict__ ss,
        const float* __restrict__ hbuf, const float* __restrict__ hbb,
        float* __restrict__ cglob, float* __restrict__ pg, float* __restrict__ pcs,
        float* __restrict__ outz, int last) {
    int l = blockIdx.x, idx0 = l >> 3;
    int b = (l & 7) + ((idx0 >> 5) << 3);
    int j = idx0 & 31;
    int t = threadIdx.x;  // 256
    int n0 = j * 32;
    __shared__ __align__(16) float sy[32 * 128];    // 16KB (affine-applied y chunk)
    __shared__ __align__(16) float sh[16 * 132];    // padded rows
    __shared__ float sss[256];
    __shared__ float swn[32];
    __shared__ float shb[16];
    __shared__ float scd[32][17];
    {
        if (t < 256) sss[t] = ss[t];
        if (t < 32) swn[t] = wsum[((size_t)b << 10) + n0 + t];
        if (t < 16) shb[t] = hbb[b * 16 + t];
        const float4* hb4 = (const float4*)(hbuf + (size_t)b * 16 * NCI);
        float4* sh4 = (float4*)sh;
        for (int jj = t; jj < 16 * 32; jj += 256) {
            int row = jj >> 5, col = jj & 31;
            sh4[row * 33 + col] = hb4[row * 32 + col];
        }
    }
    __syncthreads();
    {
        const float4* yb4 = (const float4*)(yraw + (((size_t)b << 10) + n0) * NCI);
        float4* sy4 = (float4*)sy;
        const float4* sc4 = (const float4*)sss;
        const float4* sh4p = (const float4*)(sss + 128);
        for (int jj = t; jj < 32 * 32; jj += 256) {
            int row = jj >> 5, col = jj & 31;
            float4 v = yb4[jj];
            float4 sc = sc4[col], shf = sh4p[col];
            float wn = swn[row];
            float4 o;
            o.x = sc.x * v.x + shf.x * wn;
            o.y = sc.y * v.y + shf.y * wn;
            o.z = sc.z * v.z + shf.z * wn;
            o.w = sc.w * v.w + shf.w * wn;
            sy4[jj] = o;
        }
    }
    __syncthreads();
    int nsub = t >> 4, d = t & 15;
    #pragma unroll
    for (int nn = nsub; nn < 32; nn += 16) {
        float acc = 0.f;
        const float* yr = &sy[nn * 128];
        const float* hr = &sh[d * 132];
        #pragma unroll 8
        for (int i = 0; i < 128; i += 4) {
            float4 a = *(const float4*)&yr[i];
            float4 h4 = *(const float4*)&hr[i];
            acc = fmaf(a.x, h4.x, acc);
            acc = fmaf(a.y, h4.y, acc);
            acc = fmaf(a.z, h4.z, acc);
            acc = fmaf(a.w, h4.w, acc);
        }
        scd[nn][d] = acc + shb[d];
    }
    __syncthreads();
    if (t < 32) {
        float z[16], zs[16];
        #pragma unroll
        for (int d2 = 0; d2 < 16; ++d2) { z[d2] = scd[t][d2]; zs[d2] = z[d2]; }
        #pragma unroll
        for (int a = 0; a < 16; ++a) {
            #pragma unroll
            for (int b2 = a + 1; b2 < 16; ++b2) {
                float hi = fmaxf(zs[a], zs[b2]);
                float lo = fminf(zs[a], zs[b2]);
                zs[a] = hi; zs[b2] = lo;
            }
        }
        float cs = 0.f, tausum = 0.f;
        int kz = 1;
        #pragma unroll
        for (int k = 1; k <= 16; ++k) {
            cs += zs[k - 1];
            if (1.f + (float)k * zs[k - 1] > cs) { kz = k; tausum = cs; }
        }
        float tau = (tausum - 1.f) / (float)kz;
        #pragma unroll
        for (int d2 = 0; d2 < 16; ++d2) scd[t][d2] = fmaxf(z[d2] - tau, 0.f);
    }
    __syncthreads();
    if (last) {
        for (int jj = t; jj < 32 * 16; jj += 256)
            cglob[(((size_t)b << 10) + n0 + (jj >> 4)) * ND + (jj & 15)] = scd[jj >> 4][jj & 15];
        if (j == 0) outz[VOFF_ADJ + b * 256 + t] = 0.f;   // zero adj_out region for svt atomics
    }
    if (t < 16) {
        float cs = 0.f;
        #pragma unroll 4
        for (int nn = 0; nn < 32; ++nn) cs += scd[nn][t];
        pcs[(b * 32 + j) * 16 + t] = cs;
    }
    int col = t & 127, dh = t >> 7;
    float accg[8] = {};
    for (int nn = 0; nn < 32; ++nn) {
        float yv = sy[nn * 128 + col];
        #pragma unroll
        for (int dd = 0; dd < 8; ++dd) accg[dd] = fmaf(scd[nn][dh * 8 + dd], yv, accg[dd]);
    }
    #pragma unroll
    for (int dd = 0; dd < 8; ++dd)
        pg[(((size_t)b * 32 + j) * 16 + dh * 8 + dd) * NCI + col] = accg[dd];
}

// ---- final: sv mode2 (blocks 0..255) + t2+adjout partials (blocks 256..767) -------------------
__global__ __launch_bounds__(256) void k_svt(const float* __restrict__ pg,
        const float* __restrict__ pcs, const float* __restrict__ W,
        const float* __restrict__ Wt, const float* __restrict__ bias,
        const float* __restrict__ xm, float* __restrict__ hbuf,
        float* __restrict__ hbb, const float* __restrict__ cglob,
        const int* __restrict__ nbr_idx, const int* __restrict__ nbr_cnt,
        const float* __restrict__ selfd, float* __restrict__ outv) {
    __shared__ float gl[128], svec[128], vvv[128];
    __shared__ float4 red[8][32];
    __shared__ float redf[256];
    __shared__ float csum_s, scal;
    __shared__ float cm[32][17], tm[32][17];
    int t = threadIdx.x;
    if (blockIdx.x < 256) {
        int l = blockIdx.x, idx0 = l >> 3;
        int b = (l & 7) + ((idx0 >> 4) << 3);
        int d = idx0 & 15;
        sv_phase(b, d, t, 2, 0, pg, pg, pg, pcs, W, Wt, bias, xm,
                 hbuf, hbb, outv, gl, red, redf, svec, vvv, &csum_s, &scal);
        return;
    }
    int l2 = blockIdx.x - 256, idx0 = l2 >> 3;
    int b = (l2 & 7) + ((idx0 >> 5) << 3);
    int j = idx0 & 31;
    for (int jj = t; jj < 32 * 16; jj += 256)
        cm[jj >> 4][jj & 15] = cglob[(((size_t)b << 10) + j * 32 + (jj >> 4)) * ND + (jj & 15)];
    __syncthreads();
    int w = t >> 6, tg = t & 63, nsub = tg >> 4, d = tg & 15;
    for (int mm = w; mm < 32; mm += 4) {
        int m = j * 32 + mm;
        int bm = (b << 10) + m;
        int cnt = nbr_cnt[bm];
        float acc = 0.f;
        for (int k = nsub; k < cnt; k += 4) {
            int n = nbr_idx[(size_t)bm * MAXDEG + k];
            acc += cglob[(((size_t)b << 10) + n) * ND + d];
        }
        acc += __shfl_xor(acc, 16);
        acc += __shfl_xor(acc, 32);
        if (tg < 16) {
            if (selfd[bm] == 0.f) acc -= cm[mm][d];
            tm[mm][d] = acc;
        }
    }
    __syncthreads();
    int d2 = t >> 4, e2 = t & 15;
    float s = 0.f;
    #pragma unroll 8
    for (int mm = 0; mm < 32; ++mm) s = fmaf(tm[mm][d2], cm[mm][e2], s);
    atomicAdd(&outv[VOFF_ADJ + b * 256 + t], s);
}

extern "C" void kernel_launch(void* const* d_in, const int* in_sizes, int n_in,
                              void* d_out, int out_size, void* d_ws, size_t ws_size,
                              hipStream_t stream) {
    const float* x     = (const float*)d_in[0];
    const float* adj   = (const float*)d_in[1];
    const float* gamma = (const float*)d_in[2];
    const float* beta  = (const float*)d_in[3];
    const float* W     = (const float*)d_in[4];
    const float* bias  = (const float*)d_in[5];
    float* out = (float*)d_out;

    char* wptr = (char*)d_ws;
    size_t used = 0;
    auto alloc = [&](size_t nbytes) -> void* {
        void* p = wptr + used;
        used += (nbytes + 255) & ~(size_t)255;
        return p;
    };
    float* pbn     = (float*)alloc((size_t)256 * 256 * 4);
    float* ss      = (float*)alloc(256 * 4);
    float* xm      = (float*)alloc((size_t)NB * NCI * 4);
    float* dis     = (float*)alloc((size_t)NB * NN * 4);
    float* selfd   = (float*)alloc((size_t)NB * NN * 4);
    int*   nbr_cnt = (int*)alloc((size_t)NB * NN * 4);
    float* Wt      = (float*)alloc((size_t)ND * NCI * NCO * 4);
    float* yraw    = (float*)alloc((size_t)NB * NN * NCI * 4);
    float* wsum    = (float*)alloc((size_t)NB * NN * 4);
    float* cglob   = (float*)alloc((size_t)NB * NN * ND * 4);
    float* pg      = (float*)alloc((size_t)NB * 32 * ND * NCI * 4);
    float* pcs     = (float*)alloc((size_t)NB * 32 * ND * 4);
    float* hbuf    = (float*)alloc((size_t)NB * ND * NCI * 4);
    float* hbb     = (float*)alloc((size_t)NB * ND * 4);
    int*   nbr_idx = (int*)alloc((size_t)NB * NN * MAXDEG * 4);
    if (used > ws_size) return;

    // 1: BN stats + Wt + neighbor lists (adj read once)
    k_pre1<<<272 + NB * NN, 256, 0, stream>>>(x, pbn, W, Wt, adj, dis,
                                              nbr_idx, nbr_cnt, selfd);
    // 2: BN finalize + yraw gather (affine deferred)
    k_pre2<<<16 + NB * NN, 128, 0, stream>>>(x, dis, nbr_idx, nbr_cnt, yraw, wsum,
                                             pbn, gamma, beta, ss, xm);
    // 3: sv iter0 (uniform c; g from yraw colsum) -> h1
    k_sv<<<NB * ND, 256, 0, stream>>>(yraw, wsum, ss, pcs, W, Wt, bias, xm,
                                      hbuf, hbb, out, 0, 0);
    // 4: bgc iter1 (logits = y.h1 + hbb1)
    k_bgc<<<NB * 32, 256, 0, stream>>>(yraw, wsum, ss, hbuf, hbb, cglob, pg, pcs, out, 0);
    // 5: sv iter1 -> h accumulated (h1+h2)
    k_sv<<<NB * ND, 256, 0, stream>>>(pg, wsum, ss, pcs, W, Wt, bias, xm,
                                      hbuf, hbb, out, 1, 1);
    // 6: bgc iter2 (logits = y.(h1+h2) + hbb1+hbb2; final c; zero adj region)
    k_bgc<<<NB * 32, 256, 0, stream>>>(yraw, wsum, ss, hbuf, hbb, cglob, pg, pcs, out, 1);
    // 7: final v output + coarsened adjacency
    k_svt<<<256 + NB * 32, 256, 0, stream>>>(pg, pcs, W, Wt, bias, xm, hbuf, hbb,
                                             cglob, nbr_idx, nbr_cnt, selfd, out);
}